// Round 1
// baseline (571.386 us; speedup 1.0000x reference)
//
#include <hip/hip_runtime.h>

#define NN 8192
#define TILE 64

// ---------------------------------------------------------------------------
// Pass 1: rowsum[i] = sum_j relu((A[i][j] + A[j][i]) * 0.5)
// (self-loop +1 is folded into the rsqrt in pass 2)
// Block = 256 threads handles a 64x64 tile (bi,bj). Loads the (bi,bj) tile
// and the (bj,bi) tile coalesced (float4), transposes through LDS (+1 pad:
// stride 65 == 1 mod 32 -> conflict-free both directions).
// ---------------------------------------------------------------------------
__global__ __launch_bounds__(256) void rowsum_kernel(const float* __restrict__ A,
                                                     float* __restrict__ rowsum) {
    __shared__ float la[TILE][TILE + 1];
    __shared__ float lb[TILE][TILE + 1];

    const int bi = blockIdx.y, bj = blockIdx.x;
    const int gi0 = bi * TILE, gj0 = bj * TILE;
    const int t  = threadIdx.x;
    const int lc = t & 15;   // column group of 4 floats (0..15)
    const int lr = t >> 4;   // row within pass (0..15)

#pragma unroll
    for (int p = 0; p < 4; ++p) {
        const int r = lr + 16 * p;
        const float4 va = *(const float4*)&A[(size_t)(gi0 + r) * NN + gj0 + lc * 4];
        la[r][lc * 4 + 0] = va.x; la[r][lc * 4 + 1] = va.y;
        la[r][lc * 4 + 2] = va.z; la[r][lc * 4 + 3] = va.w;
        const float4 vb = *(const float4*)&A[(size_t)(gj0 + r) * NN + gi0 + lc * 4];
        lb[r][lc * 4 + 0] = vb.x; lb[r][lc * 4 + 1] = vb.y;
        lb[r][lc * 4 + 2] = vb.z; lb[r][lc * 4 + 3] = vb.w;
    }
    __syncthreads();

#pragma unroll
    for (int p = 0; p < 4; ++p) {
        const int r = lr + 16 * p;
        float s = 0.0f;
#pragma unroll
        for (int u = 0; u < 4; ++u) {
            const int c = lc * 4 + u;
            const float v = (la[r][c] + lb[c][r]) * 0.5f;
            s += fmaxf(v, 0.0f);
        }
        // reduce across the 16 lanes sharing row r (lanes 16*lr .. 16*lr+15)
        s += __shfl_xor(s, 1);
        s += __shfl_xor(s, 2);
        s += __shfl_xor(s, 4);
        s += __shfl_xor(s, 8);
        if (lc == 0) atomicAdd(&rowsum[gi0 + r], s);
    }
}

// ---------------------------------------------------------------------------
// Pass 2: out[i][j] = (relu((A[i][j]+A[j][i])*0.5) + (i==j)) * rinv[i]*rinv[j]
// with rinv[i] = rsqrt(rowsum[i] + 1)  (+1 = self loop; rowsum+1 >= 1 so
// never inf -> the reference's isinf guard is vacuous)
// ---------------------------------------------------------------------------
__global__ __launch_bounds__(256) void normalize_kernel(const float* __restrict__ A,
                                                        const float* __restrict__ rowsum,
                                                        float* __restrict__ out) {
    __shared__ float la[TILE][TILE + 1];
    __shared__ float lb[TILE][TILE + 1];
    __shared__ float ri[TILE];
    __shared__ float rj[TILE];

    const int bi = blockIdx.y, bj = blockIdx.x;
    const int gi0 = bi * TILE, gj0 = bj * TILE;
    const int t  = threadIdx.x;
    const int lc = t & 15;
    const int lr = t >> 4;

#pragma unroll
    for (int p = 0; p < 4; ++p) {
        const int r = lr + 16 * p;
        const float4 va = *(const float4*)&A[(size_t)(gi0 + r) * NN + gj0 + lc * 4];
        la[r][lc * 4 + 0] = va.x; la[r][lc * 4 + 1] = va.y;
        la[r][lc * 4 + 2] = va.z; la[r][lc * 4 + 3] = va.w;
        const float4 vb = *(const float4*)&A[(size_t)(gj0 + r) * NN + gi0 + lc * 4];
        lb[r][lc * 4 + 0] = vb.x; lb[r][lc * 4 + 1] = vb.y;
        lb[r][lc * 4 + 2] = vb.z; lb[r][lc * 4 + 3] = vb.w;
    }
    if (t < TILE) {
        ri[t] = rsqrtf(rowsum[gi0 + t] + 1.0f);
    } else if (t < 2 * TILE) {
        rj[t - TILE] = rsqrtf(rowsum[gj0 + t - TILE] + 1.0f);
    }
    __syncthreads();

#pragma unroll
    for (int p = 0; p < 4; ++p) {
        const int r  = lr + 16 * p;
        const int gi = gi0 + r;
        float vals[4];
#pragma unroll
        for (int u = 0; u < 4; ++u) {
            const int c  = lc * 4 + u;
            const int gj = gj0 + c;
            float v = (la[r][c] + lb[c][r]) * 0.5f;
            v = fmaxf(v, 0.0f);
            if (gi == gj) v += 1.0f;
            vals[u] = v * ri[r] * rj[c];
        }
        float4 o = make_float4(vals[0], vals[1], vals[2], vals[3]);
        *(float4*)&out[(size_t)gi * NN + gj0 + lc * 4] = o;
    }
}

extern "C" void kernel_launch(void* const* d_in, const int* in_sizes, int n_in,
                              void* d_out, int out_size, void* d_ws, size_t ws_size,
                              hipStream_t stream) {
    const float* A   = (const float*)d_in[0];
    float*       out = (float*)d_out;
    float*       rowsum = (float*)d_ws;   // NN floats = 32 KB

    hipMemsetAsync(rowsum, 0, NN * sizeof(float), stream);

    dim3 grid(NN / TILE, NN / TILE);
    rowsum_kernel<<<grid, 256, 0, stream>>>(A, rowsum);
    normalize_kernel<<<grid, 256, 0, stream>>>(A, rowsum, out);
}

// Round 2
// 541.548 us; speedup vs baseline: 1.0551x; 1.0551x over previous
//
#include <hip/hip_runtime.h>

#define NN 8192
#define TILE 64

// Symmetry: sym(i,j) = relu((A[i][j]+A[j][i])/2) = sym(j,i), and the final
// normalized matrix is symmetric too. Only blocks with bi <= bj do work;
// each covers both the (bi,bj) and (bj,bi) output tiles.

// ---------------------------------------------------------------------------
// Pass 1: rowsum[i] = sum_j sym(i,j).  Block (bi<=bj) reads tiles (bi,bj) and
// (bj,bi) once, contributes row-sums for the bi rows AND (via column sums of
// the same tile) row-sums for the bj rows. Self-loop +1 folded into pass 2.
// ---------------------------------------------------------------------------
__global__ __launch_bounds__(256) void rowsum_kernel(const float* __restrict__ A,
                                                     float* __restrict__ rowsum) {
    const int bi = blockIdx.y, bj = blockIdx.x;
    if (bj < bi) return;                       // lower-triangle blocks idle

    __shared__ float la[TILE][TILE + 1];
    __shared__ float lb[TILE][TILE + 1];
    __shared__ float cs[TILE];                 // column partial sums

    const int gi0 = bi * TILE, gj0 = bj * TILE;
    const int t  = threadIdx.x;
    const int lc = t & 15;                     // 0..15 : group of 4 columns
    const int lr = t >> 4;                     // 0..15 : row in each pass

    if (t < TILE) cs[t] = 0.0f;

#pragma unroll
    for (int p = 0; p < 4; ++p) {
        const int r = lr + 16 * p;
        const float4 va = *(const float4*)&A[(size_t)(gi0 + r) * NN + gj0 + lc * 4];
        la[r][lc * 4 + 0] = va.x; la[r][lc * 4 + 1] = va.y;
        la[r][lc * 4 + 2] = va.z; la[r][lc * 4 + 3] = va.w;
        const float4 vb = *(const float4*)&A[(size_t)(gj0 + r) * NN + gi0 + lc * 4];
        lb[r][lc * 4 + 0] = vb.x; lb[r][lc * 4 + 1] = vb.y;
        lb[r][lc * 4 + 2] = vb.z; lb[r][lc * 4 + 3] = vb.w;
    }
    __syncthreads();

    float colpart[4] = {0.f, 0.f, 0.f, 0.f};
#pragma unroll
    for (int p = 0; p < 4; ++p) {
        const int r = lr + 16 * p;
        float s = 0.0f;
#pragma unroll
        for (int u = 0; u < 4; ++u) {
            const int c = lc * 4 + u;
            const float v = fmaxf((la[r][c] + lb[c][r]) * 0.5f, 0.0f);
            s += v;
            colpart[u] += v;
        }
        // row reduction across the 16 contiguous lanes sharing row r
        s += __shfl_xor(s, 1);
        s += __shfl_xor(s, 2);
        s += __shfl_xor(s, 4);
        s += __shfl_xor(s, 8);
        if (lc == 0) atomicAdd(&rowsum[gi0 + r], s);
    }

    if (bi != bj) {
        // column sums = row sums for the bj rows. Reduce colpart over the
        // 4 lr values inside this wave (lanes differ by 16, 32), then LDS.
#pragma unroll
        for (int u = 0; u < 4; ++u) {
            colpart[u] += __shfl_xor(colpart[u], 16);
            colpart[u] += __shfl_xor(colpart[u], 32);
        }
        if ((t & 48) == 0) {        // one lane per (wave, column-group)
#pragma unroll
            for (int u = 0; u < 4; ++u) atomicAdd(&cs[lc * 4 + u], colpart[u]);
        }
        __syncthreads();
        if (t < TILE) atomicAdd(&rowsum[gj0 + t], cs[t]);
    }
}

// ---------------------------------------------------------------------------
// Pass 2: out[i][j] = (sym(i,j) + (i==j)) * rinv[i] * rinv[j],
// rinv[i] = rsqrt(rowsum[i] + 1). Block (bi<=bj) writes tile (bi,bj)
// coalesced, stores the scaled tile back into la, then writes the transposed
// tile at (bj,bi) coalesced (out is symmetric).
// ---------------------------------------------------------------------------
__global__ __launch_bounds__(256) void normalize_kernel(const float* __restrict__ A,
                                                        const float* __restrict__ rowsum,
                                                        float* __restrict__ out) {
    const int bi = blockIdx.y, bj = blockIdx.x;
    if (bj < bi) return;

    __shared__ float la[TILE][TILE + 1];
    __shared__ float lb[TILE][TILE + 1];
    __shared__ float ri[TILE];
    __shared__ float rj[TILE];

    const int gi0 = bi * TILE, gj0 = bj * TILE;
    const int t  = threadIdx.x;
    const int lc = t & 15;
    const int lr = t >> 4;

#pragma unroll
    for (int p = 0; p < 4; ++p) {
        const int r = lr + 16 * p;
        const float4 va = *(const float4*)&A[(size_t)(gi0 + r) * NN + gj0 + lc * 4];
        la[r][lc * 4 + 0] = va.x; la[r][lc * 4 + 1] = va.y;
        la[r][lc * 4 + 2] = va.z; la[r][lc * 4 + 3] = va.w;
        const float4 vb = *(const float4*)&A[(size_t)(gj0 + r) * NN + gi0 + lc * 4];
        lb[r][lc * 4 + 0] = vb.x; lb[r][lc * 4 + 1] = vb.y;
        lb[r][lc * 4 + 2] = vb.z; lb[r][lc * 4 + 3] = vb.w;
    }
    if (t < TILE) {
        ri[t] = rsqrtf(rowsum[gi0 + t] + 1.0f);
    } else if (t < 2 * TILE) {
        rj[t - TILE] = rsqrtf(rowsum[gj0 + t - TILE] + 1.0f);
    }
    __syncthreads();

#pragma unroll
    for (int p = 0; p < 4; ++p) {
        const int r  = lr + 16 * p;
        const int gi = gi0 + r;
        float vals[4];
#pragma unroll
        for (int u = 0; u < 4; ++u) {
            const int c  = lc * 4 + u;
            const int gj = gj0 + c;
            float v = fmaxf((la[r][c] + lb[c][r]) * 0.5f, 0.0f);
            if (gi == gj) v += 1.0f;
            vals[u] = v * ri[r] * rj[c];
            la[r][c] = vals[u];   // same thread read la[r][c] above — no race
        }
        *(float4*)&out[(size_t)gi * NN + gj0 + lc * 4] =
            make_float4(vals[0], vals[1], vals[2], vals[3]);
    }

    if (bi != bj) {
        __syncthreads();
        // transposed tile: out[gj0+r'][gi0+c'] = scaled(c', r') = la[c'][r']
#pragma unroll
        for (int p = 0; p < 4; ++p) {
            const int r2 = lr + 16 * p;          // row within the bj tile
            float vals[4];
#pragma unroll
            for (int u = 0; u < 4; ++u) {
                const int c2 = lc * 4 + u;       // col within the bi tile
                vals[u] = la[c2][r2];            // stride-65 col read: 2-way, free
            }
            *(float4*)&out[(size_t)(gj0 + r2) * NN + gi0 + lc * 4] =
                make_float4(vals[0], vals[1], vals[2], vals[3]);
        }
    }
}

extern "C" void kernel_launch(void* const* d_in, const int* in_sizes, int n_in,
                              void* d_out, int out_size, void* d_ws, size_t ws_size,
                              hipStream_t stream) {
    const float* A   = (const float*)d_in[0];
    float*       out = (float*)d_out;
    float*       rowsum = (float*)d_ws;   // NN floats = 32 KB

    hipMemsetAsync(rowsum, 0, NN * sizeof(float), stream);

    dim3 grid(NN / TILE, NN / TILE);
    rowsum_kernel<<<grid, 256, 0, stream>>>(A, rowsum);
    normalize_kernel<<<grid, 256, 0, stream>>>(A, rowsum, out);
}